// Round 2
// baseline (826.426 us; speedup 1.0000x reference)
//
#include <hip/hip_runtime.h>
#include <math.h>

// ExpressiveUpdateRule: out[b,o,i] = W[b,o,i] - scale_b * (W[b,o,:]·x_b - g[b,o]) * x_b[i]
// scale_b = 1 / (LAMBDA_SQ + softplus(x_b·eta_w + eta_b))
// B=128, D=1024, fp32. Memory-bound: 512 MiB read (W once) + 512 MiB write.
// R1: flattened per-wave row loop -> 16 W-loads in flight per wave,
//     4 independent shfl-reduce chains, x in regs (no LDS/barrier), nt loads/stores.
// R2: fused scale computation into the update kernel (single dispatch);
//     eta dot is recomputed per-wave and hides fully under the W-load latency.

typedef float f4 __attribute__((ext_vector_type(4)));

constexpr int D = 1024;
constexpr float LAMBDA_SQ = 1024.0f;
constexpr int ROWS_PER_WAVE = 4;
constexpr int WAVES_PER_BLOCK = 4;
constexpr int ROWS_PER_BLOCK = ROWS_PER_WAVE * WAVES_PER_BLOCK;   // 16
constexpr int BLOCKS_PER_BATCH = D / ROWS_PER_BLOCK;              // 64

// Fused kernel: per-wave scale recompute + matvec + rank-1 update, one burst.
// Each wave owns 4 consecutive rows: issue x/eta/W loads back-to-back (24 loads
// in flight), compute scale while W lands, then 4 interleaved butterfly
// reductions, then 16 streaming stores. No LDS, no barriers, no workspace.
__global__ __launch_bounds__(256, 4) void update_kernel(const float* __restrict__ W,
                                                        const float* __restrict__ x,
                                                        const float* __restrict__ g,
                                                        const float* __restrict__ eta_w,
                                                        const float* __restrict__ eta_b,
                                                        float* __restrict__ out) {
    const int tid  = threadIdx.x;
    const int b    = blockIdx.x / BLOCKS_PER_BATCH;
    const int row0 = (blockIdx.x % BLOCKS_PER_BATCH) * ROWS_PER_BLOCK;
    const int wave = tid >> 6;
    const int lane = tid & 63;
    const int row  = row0 + wave * ROWS_PER_WAVE;   // this wave: rows row..row+3

    // g[b, row..row+3]: row is 4-aligned -> one broadcast float4 load, issued early
    const f4 gv = *(const f4*)(g + (size_t)b * D + row);
    const float eb = eta_b[0];

    // x[b,:] into regs (L1/L2-resident: reused by 64 blocks per batch)
    const f4* __restrict__ xv = (const f4*)(x + (size_t)b * D);
    f4 xreg[4];
    #pragma unroll
    for (int c = 0; c < 4; ++c) xreg[c] = xv[c * 64 + lane];

    // eta_w into regs (4 KiB, L2-resident after first block)
    const f4* __restrict__ ev = (const f4*)eta_w;
    f4 ereg[4];
    #pragma unroll
    for (int c = 0; c < 4; ++c) ereg[c] = ev[c * 64 + lane];

    const size_t base = ((size_t)b * D + row) * D;
    const f4* __restrict__ wrow = (const f4*)(W + base);
    f4* __restrict__ orow = (f4*)(out + base);

    // issue ALL W loads: 16 x global_load_dwordx4 in flight per lane
    f4 wreg[ROWS_PER_WAVE][4];
    #pragma unroll
    for (int r = 0; r < ROWS_PER_WAVE; ++r) {
        #pragma unroll
        for (int c = 0; c < 4; ++c) {
            wreg[r][c] = __builtin_nontemporal_load(&wrow[(size_t)r * (D / 4) + c * 64 + lane]);
        }
    }

    // ---- scale recompute, hidden under W-load latency (only needs x/eta) ----
    float p = 0.0f;
    #pragma unroll
    for (int c = 0; c < 4; ++c) {
        p += ereg[c].x * xreg[c].x + ereg[c].y * xreg[c].y
           + ereg[c].z * xreg[c].z + ereg[c].w * xreg[c].w;
    }
    #pragma unroll
    for (int off = 32; off > 0; off >>= 1) p += __shfl_xor(p, off);
    const float z = p + eb;
    const float sp = fmaxf(z, 0.0f) + log1pf(expf(-fabsf(z)));   // stable softplus
    const float s = 1.0f / (LAMBDA_SQ + sp);

    // ---- per-row partial dots (compiler waits vmcnt per row as data lands) ----
    float dot[ROWS_PER_WAVE];
    #pragma unroll
    for (int r = 0; r < ROWS_PER_WAVE; ++r) {
        float d = 0.0f;
        #pragma unroll
        for (int c = 0; c < 4; ++c) {
            d += wreg[r][c].x * xreg[c].x + wreg[r][c].y * xreg[c].y
               + wreg[r][c].z * xreg[c].z + wreg[r][c].w * xreg[c].w;
        }
        dot[r] = d;
    }

    // 4 independent 64-lane butterflies, interleaved (6 steps, 4-wide ILP)
    #pragma unroll
    for (int off = 32; off > 0; off >>= 1) {
        #pragma unroll
        for (int r = 0; r < ROWS_PER_WAVE; ++r) dot[r] += __shfl_xor(dot[r], off);
    }

    // rewrite rows from registers; streaming stores
    #pragma unroll
    for (int r = 0; r < ROWS_PER_WAVE; ++r) {
        const float f = s * (dot[r] - gv[r]);
        #pragma unroll
        for (int c = 0; c < 4; ++c) {
            f4 o;
            o.x = wreg[r][c].x - f * xreg[c].x;
            o.y = wreg[r][c].y - f * xreg[c].y;
            o.z = wreg[r][c].z - f * xreg[c].z;
            o.w = wreg[r][c].w - f * xreg[c].w;
            __builtin_nontemporal_store(o, &orow[(size_t)r * (D / 4) + c * 64 + lane]);
        }
    }
}

extern "C" void kernel_launch(void* const* d_in, const int* in_sizes, int n_in,
                              void* d_out, int out_size, void* d_ws, size_t ws_size,
                              hipStream_t stream) {
    const float* W     = (const float*)d_in[0];
    const float* x     = (const float*)d_in[1];
    const float* g     = (const float*)d_in[2];
    const float* eta_w = (const float*)d_in[3];
    const float* eta_b = (const float*)d_in[4];
    float* out = (float*)d_out;

    const int B = in_sizes[1] / D;  // 128
    update_kernel<<<B * BLOCKS_PER_BATCH, 256, 0, stream>>>(W, x, g, eta_w, eta_b, out);
}